// Round 8
// baseline (10491.303 us; speedup 1.0000x reference)
//
#include <hip/hip_runtime.h>
#include <math.h>

#define T_LEN 4096
#define EDIM  256
#define HDIM  512
#define NTAGS 50
#define SENTH 0xFFFFu   // bf16 -NaN sentinel; o*tanh(c) can never produce it

typedef unsigned short u16;
typedef unsigned int   u32;
typedef unsigned long long u64;

__device__ __forceinline__ float sigm(float x) { return 1.0f / (1.0f + expf(-x)); }
__device__ __forceinline__ float bf2f(u32 b) { union { u32 i; float f; } v; v.i = b << 16; return v.f; }
__device__ __forceinline__ u32 f2bf(float f) {
    union { float f; u32 i; } v; v.f = f;
    return (v.i + 0x7fffu + ((v.i >> 16) & 1u)) >> 16;   // RNE
}
__device__ __forceinline__ int shfl_i(int v, int l) { return __shfl(v, l, 64); }

// ---------------------------------------------------------------------------
// Persistent bidirectional LSTM scan. R8 = R4's proven sync skeleton with the
// hot-line traffic minimized:
//   - h exchanged as PACKED BF16 (hs = u16[T][512] per dir): a wave's quarter
//     is 256B = 4 cache lines (was 8); producer WG output is 32B (was 64B).
//   - Producer: wave-0 finalize, h packed via shfl into 4 u64 agent stores
//     (was 16 dword stores) — 4 MALL transactions per WG per step.
//   - Consumer: 3-deep poll pipeline (detection quantum ~ RTT/3), each wave
//     polls ONLY its own quarter: 1 u32/lane, relaxed agent loads.
// Topology (R4-proven): 64 WGs x 256 thr; blocks 0..31 fwd, 32..63 bwd.
// WG g owns units [g*16,+16) => 64 gate rows; lane = row,
// R = (lane>>4)*512 + g*16 + (lane&15); wave wv owns column quarter.
// Matvec (R7-style): x and h staged into wave-private LDS strips
// (same-wave ds_write->ds_read ordered by lgkmcnt, no barrier), then
// 64 + 128 pure v_fmac from register weights. Partials to pl[parity][.],
// ONE __syncthreads, wave 0 finalizes (4-quarter sum, shfl gate-gather,
// activations on lanes 0..15, bf16 pack, 4 u64 stores).
// pl parity race-freedom: rewrite of pl[s&1] at s+2 requires passing
// barrier(s+1), which wave 0 only reaches after its step-s read. QED.
// ---------------------------------------------------------------------------
__global__ __launch_bounds__(256, 1) void lstm_scan(
    const int* __restrict__ sent, const float* __restrict__ emb,
    const float* __restrict__ Wih_f, const float* __restrict__ Whh_f,
    const float* __restrict__ bih_f, const float* __restrict__ bhh_f,
    const float* __restrict__ Wih_b, const float* __restrict__ Whh_b,
    const float* __restrict__ bih_b, const float* __restrict__ bhh_b,
    u16* hsf, u16* hsb)
{
    const int tid  = threadIdx.x;
    const int lane = tid & 63;
    const int wv   = tid >> 6;          // 0..3 = column quarter
    const int dir  = blockIdx.x >> 5;
    const int g    = blockIdx.x & 31;

    const float* Wih = dir ? Wih_b : Wih_f;
    const float* Whh = dir ? Whh_b : Whh_f;
    const float* bih = dir ? bih_b : bih_f;
    const float* bhh = dir ? bhh_b : bhh_f;
    u16* hs = dir ? hsb : hsf;

    // Lane = row. R = q*512 + g*16 + u, q = lane>>4, u = lane&15.
    const int R = (lane >> 4) * 512 + g * 16 + (lane & 15);

    float wh[128];
    {
        const float* base = Whh + (size_t)R * HDIM + wv * 128;
        #pragma unroll
        for (int i = 0; i < 32; ++i) {
            float4 v = *(const float4*)(base + 4 * i);
            wh[4*i] = v.x; wh[4*i+1] = v.y; wh[4*i+2] = v.z; wh[4*i+3] = v.w;
        }
    }
    float wx[64];
    {
        const float* base = Wih + (size_t)R * EDIM + wv * 64;
        #pragma unroll
        for (int i = 0; i < 16; ++i) {
            float4 v = *(const float4*)(base + 4 * i);
            wx[4*i] = v.x; wx[4*i+1] = v.y; wx[4*i+2] = v.z; wx[4*i+3] = v.w;
        }
    }
    const float bias = bih[R] + bhh[R];   // used by wave 0 finalize (lane=row)

    __shared__ __align__(16) float hl[512];   // wave-private strips [wv*128,+128)
    __shared__ __align__(16) float xl[256];   // wave-private strips [wv*64,+64)
    __shared__ float pl[2][260];              // quarter qq at offset qq*65

    float c_state = 0.0f;                     // meaningful on wave0 lanes 0..15

    float ecur;
    {
        int t0 = dir ? (T_LEN - 1) : 0;
        ecur = emb[(size_t)sent[t0] * EDIM + wv * 64 + lane];
    }

    for (int s = 0; s < T_LEN; ++s) {
        const int t = dir ? (T_LEN - 1 - s) : s;

        // 1. Issue 3-deep poll pipeline FIRST.
        const u32* hp = nullptr;
        u32 v0 = 0, v1 = 0, v2 = 0;
        if (s > 0) {
            const int tp = dir ? (t + 1) : (t - 1);
            hp = (const u32*)(hs + (size_t)tp * HDIM + wv * 128) + lane;
            v0 = __hip_atomic_load(hp, __ATOMIC_RELAXED, __HIP_MEMORY_SCOPE_AGENT);
            v1 = __hip_atomic_load(hp, __ATOMIC_RELAXED, __HIP_MEMORY_SCOPE_AGENT);
            v2 = __hip_atomic_load(hp, __ATOMIC_RELAXED, __HIP_MEMORY_SCOPE_AGENT);
        }

        // 2. Prefetch next step's embedding value (h-independent).
        float enext = 0.0f;
        if (s + 1 < T_LEN) {
            int tn = dir ? (t - 1) : (t + 1);
            enext = emb[(size_t)sent[tn] * EDIM + wv * 64 + lane];
        }

        // 3. x-part: wave-private LDS broadcast + 64 pure FMAs.
        xl[wv * 64 + lane] = ecur;
        float r;
        {
            float4 x4 = *(const float4*)(xl + wv * 64);
            r = wx[0] * x4.x;
            r = fmaf(wx[1], x4.y, r);
            r = fmaf(wx[2], x4.z, r);
            r = fmaf(wx[3], x4.w, r);
            #pragma unroll
            for (int c = 1; c < 16; ++c) {
                float4 xv = *(const float4*)(xl + wv * 64 + 4 * c);
                r = fmaf(wx[4*c+0], xv.x, r);
                r = fmaf(wx[4*c+1], xv.y, r);
                r = fmaf(wx[4*c+2], xv.z, r);
                r = fmaf(wx[4*c+3], xv.w, r);
            }
        }

        // 4. Resolve poll (own quarter, 2 bf16 per lane); stage f32 to strip.
        if (s == 0) {
            hl[wv * 128 + 2 * lane]     = 0.0f;
            hl[wv * 128 + 2 * lane + 1] = 0.0f;
        } else {
            while (((v0 & 0xFFFFu) == SENTH) || ((v0 >> 16) == SENTH)) {
                v0 = v1; v1 = v2;
                v2 = __hip_atomic_load(hp, __ATOMIC_RELAXED, __HIP_MEMORY_SCOPE_AGENT);
            }
            hl[wv * 128 + 2 * lane]     = bf2f(v0 & 0xFFFFu);
            hl[wv * 128 + 2 * lane + 1] = bf2f(v0 >> 16);
        }
        // Same-wave ds_write -> ds_read: ordered by lgkmcnt, no barrier.

        // 5. h-part: 32 broadcast ds_read_b128 + 128 pure FMAs.
        if (s > 0) {
            #pragma unroll
            for (int c = 0; c < 32; ++c) {
                float4 hv = *(const float4*)(hl + wv * 128 + 4 * c);
                r = fmaf(wh[4*c+0], hv.x, r);
                r = fmaf(wh[4*c+1], hv.y, r);
                r = fmaf(wh[4*c+2], hv.z, r);
                r = fmaf(wh[4*c+3], hv.w, r);
            }
        }

        // 6. Publish partial, one barrier.
        pl[s & 1][wv * 65 + lane] = r;
        __syncthreads();

        // 7. Wave-0 finalize: all 16 units, then 4 packed u64 stores.
        if (wv == 0) {
            const float* pb = pl[s & 1];
            float vsum = pb[lane] + pb[65 + lane] + pb[130 + lane] + pb[195 + lane] + bias;
            const int u = lane & 15;
            float gi = __shfl(vsum, u,      64);
            float gf = __shfl(vsum, u + 16, 64);
            float gg = __shfl(vsum, u + 32, 64);
            float go = __shfl(vsum, u + 48, 64);

            float iv = sigm(gi), fv = sigm(gf);
            float gv = tanhf(gg), ov = sigm(go);
            c_state = fv * c_state + iv * gv;
            float h = ov * tanhf(c_state);

            int b16 = (int)f2bf(h);           // valid on lanes 0..15
            int j0 = shfl_i(b16, 4 * lane + 0);
            int j1 = shfl_i(b16, 4 * lane + 1);
            int j2 = shfl_i(b16, 4 * lane + 2);
            int j3 = shfl_i(b16, 4 * lane + 3);
            if (lane < 4) {
                u64 pk = (u64)(u32)(j0 | (j1 << 16)) |
                         ((u64)(u32)(j2 | (j3 << 16)) << 32);
                u64* dst = (u64*)(hs + (size_t)t * HDIM + g * 16) + lane;
                __hip_atomic_store(dst, pk, __ATOMIC_RELAXED, __HIP_MEMORY_SCOPE_AGENT);
            }
        }
        ecur = enext;
    }
}

// ---------------------------------------------------------------------------
// tag_space[t] = [hs_f[t] | hs_b[t]] @ W_out^T + b_out  (f32 out, bf16 hs)
// ---------------------------------------------------------------------------
__global__ __launch_bounds__(256) void out_gemm(
    const u16* __restrict__ hsf, const u16* __restrict__ hsb,
    const float* __restrict__ Wout, const float* __restrict__ bout,
    float* __restrict__ out)
{
    const int t   = blockIdx.x;
    const int tid = threadIdx.x;
    __shared__ float h2[1024];

    {
        const u16* src = (tid < 128) ? (hsf + (size_t)t * HDIM + tid * 4)
                                     : (hsb + (size_t)t * HDIM + (tid - 128) * 4);
        float* dst = (tid < 128) ? (h2 + tid * 4) : (h2 + 512 + (tid - 128) * 4);
        u64 v = *(const u64*)src;
        dst[0] = bf2f((u32)(v      ) & 0xFFFFu);
        dst[1] = bf2f((u32)(v >> 16) & 0xFFFFu);
        dst[2] = bf2f((u32)(v >> 32) & 0xFFFFu);
        dst[3] = bf2f((u32)(v >> 48) & 0xFFFFu);
    }
    __syncthreads();

    const int wv = tid >> 6, lane = tid & 63;
    for (int tag = wv; tag < NTAGS; tag += 4) {
        const float4* wr = (const float4*)(Wout + (size_t)tag * (2 * HDIM));
        float p = 0.0f;
        #pragma unroll
        for (int c = lane; c < 256; c += 64) {
            float4 wv4 = wr[c];
            float4 hv  = *(const float4*)(h2 + c * 4);
            p += wv4.x * hv.x + wv4.y * hv.y + wv4.z * hv.z + wv4.w * hv.w;
        }
        p += __shfl_down(p, 32, 64);
        p += __shfl_down(p, 16, 64);
        p += __shfl_down(p, 8, 64);
        p += __shfl_down(p, 4, 64);
        p += __shfl_down(p, 2, 64);
        p += __shfl_down(p, 1, 64);
        if (lane == 0) out[(size_t)t * NTAGS + tag] = p + bout[tag];
    }
}

// ---------------------------------------------------------------------------
extern "C" void kernel_launch(void* const* d_in, const int* in_sizes, int n_in,
                              void* d_out, int out_size, void* d_ws, size_t ws_size,
                              hipStream_t stream)
{
    const int*   sent  = (const int*)d_in[0];
    const float* emb   = (const float*)d_in[1];
    const float* Wih_f = (const float*)d_in[2];
    const float* Whh_f = (const float*)d_in[3];
    const float* bih_f = (const float*)d_in[4];
    const float* bhh_f = (const float*)d_in[5];
    const float* Wih_b = (const float*)d_in[6];
    const float* Whh_b = (const float*)d_in[7];
    const float* bih_b = (const float*)d_in[8];
    const float* bhh_b = (const float*)d_in[9];
    const float* Wout  = (const float*)d_in[10];
    const float* bout  = (const float*)d_in[11];
    float* out = (float*)d_out;

    char* ws = (char*)d_ws;
    // Workspace: hsf u16[4096*512] @ 0 (4 MiB), hsb @ 4 MiB. Data doubles as
    // sync flag; sentinel-fill 0xFF (bf16 0xFFFF = -NaN, never produced).
    u16* hsf = (u16*)(ws);
    u16* hsb = (u16*)(ws + 4194304);
    hipMemsetAsync(ws, 0xFF, 8388608, stream);

    lstm_scan<<<64, 256, 0, stream>>>(sent, emb,
                                      Wih_f, Whh_f, bih_f, bhh_f,
                                      Wih_b, Whh_b, bih_b, bhh_b,
                                      hsf, hsb);
    out_gemm<<<T_LEN, 256, 0, stream>>>(hsf, hsb, Wout, bout, out);
}